// Round 1
// baseline (5933.270 us; speedup 1.0000x reference)
//
#include <hip/hip_runtime.h>

#define T_STEPS 2048
#define BATCH   2048
#define HIDN    128

typedef short v8s __attribute__((ext_vector_type(8)));
typedef float v4f __attribute__((ext_vector_type(4)));
typedef unsigned short u16;
typedef unsigned int   u32;

// ---------------- LDS layout (bytes) ----------------
// W1 image:  32 tiles x 4 kt x 1KB b-frag chunks      [0,       131072)
// WLIN img:  4 kt x 1KB                               [131072,  135168)
// h1 buf:    16 rows x 336B (168 shorts); cols0..127=h1, 128..131=x, rest 0
// h2 buf:    16 rows x 336B
// gates:     8 waves x 2KB ( [m 0..8][c 0..64] f32 )
#define LDS_W1    0
#define LDS_WLIN  131072
#define LDS_H1    135168
#define LDS_H2    140544
#define LDS_GATE  145920
#define LDS_TOTAL 162304
#define HROW  336   // bytes per h-buf row
#define HROWS 168   // shorts per h-buf row

__device__ __forceinline__ u16 f2bf(float x) {
    u32 u = __float_as_uint(x);
    u32 r = (u + 0x7FFFu + ((u >> 16) & 1u)) >> 16;
    return (u16)r;
}
__device__ __forceinline__ float sigf(float x) { return 1.0f / (1.0f + __expf(-x)); }
__device__ __forceinline__ float tanhf_(float x) {
    float e = __expf(2.0f * x);
    return 1.0f - 2.0f / (e + 1.0f);
}

__global__ __launch_bounds__(512, 2) void lstm_seq_kernel(
    const float* __restrict__ input,
    const float* __restrict__ W_ih1, const float* __restrict__ W_hh1,
    const float* __restrict__ b_ih1, const float* __restrict__ b_hh1,
    const float* __restrict__ W_ih2, const float* __restrict__ W_hh2,
    const float* __restrict__ b_ih2, const float* __restrict__ b_hh2,
    const float* __restrict__ W_lin, const float* __restrict__ b_lin,
    const float* __restrict__ h0,  const float* __restrict__ c0,
    const float* __restrict__ h02, const float* __restrict__ c02,
    float* __restrict__ out)
{
    extern __shared__ char smem[];
    const int tid = threadIdx.x;
    const int w   = tid >> 6;     // wave 0..7
    const int l   = tid & 63;
    const int u   = l & 15;       // MFMA "16" index
    const int q   = l >> 4;       // MFMA quad
    const int b0  = blockIdx.x * 8;

    short* h1s = (short*)(smem + LDS_H1);
    short* h2s = (short*)(smem + LDS_H2);
    float* gw  = (float*)(smem + LDS_GATE + w * 2048);

    // ---------------- init: zero h bufs ----------------
    for (int e = tid; e < 2 * 16 * HROWS; e += 512) {
        if (e < 16 * HROWS) h1s[e] = 0;
        else                h2s[e - 16 * HROWS] = 0;
    }
    __syncthreads();
    // fill h0 / h02 (rows 0..7, cols 0..127)
    for (int e = tid; e < 1024; e += 512) {
        int m = e >> 7, jj = e & 127;
        h1s[m * HROWS + jj] = (short)f2bf(h0 [(b0 + m) * HIDN + jj]);
        h2s[m * HROWS + jj] = (short)f2bf(h02[(b0 + m) * HIDN + jj]);
    }
    // x[0] into h1 buf cols 128..131
    if (tid < 8) {
        float4 xv = *(const float4*)(input + (long)(b0 + tid) * 4);
        ushort4 xb = make_ushort4(f2bf(xv.x), f2bf(xv.y), f2bf(xv.z), f2bf(xv.w));
        *(ushort4*)(h1s + tid * HROWS + 128) = xb;
    }

    // ---------------- build W1 b-frag image in LDS ----------------
    // col permutation: c = 4*j + gate  <->  original row r = gate*128 + j
    #pragma unroll
    for (int tl = 0; tl < 4; ++tl) {
        int c = (w * 4 + tl) * 16 + u;
        int r = (c & 3) * 128 + (c >> 2);
        #pragma unroll
        for (int kt = 0; kt < 4; ++kt) {
            const float* src = W_hh1 + r * 128 + kt * 32 + q * 8;
            v8s f;
            #pragma unroll
            for (int b = 0; b < 8; ++b) f[b] = (short)f2bf(src[b]);
            *(v8s*)(smem + LDS_W1 + (((w * 4 + tl) * 4 + kt) << 10) + l * 16) = f;
        }
    }
    // W_lin b-frag image (extra N-tile; cols 0..3 valid, K = h2 half)
    if (w == 7) {
        #pragma unroll
        for (int kt = 0; kt < 4; ++kt) {
            v8s f;
            #pragma unroll
            for (int b = 0; b < 8; ++b) {
                int kk = kt * 32 + q * 8 + b;
                float v = (u < 4) ? W_lin[u * 128 + kk] : 0.0f;
                f[b] = (short)f2bf(v);
            }
            *(v8s*)(smem + LDS_WLIN + (kt << 10) + l * 16) = f;
        }
    }

    // ---------------- resident register fragments ----------------
    // layer-2 weights: B[k][c], k 0..127 = W_ih2 (input h1), k 128..255 = W_hh2
    v8s w2[4][8];
    #pragma unroll
    for (int tl = 0; tl < 4; ++tl) {
        int c = (w * 4 + tl) * 16 + u;
        int r = (c & 3) * 128 + (c >> 2);
        #pragma unroll
        for (int kt = 0; kt < 8; ++kt) {
            const float* src = (kt < 4) ? (W_ih2 + r * 128 + kt * 32 + q * 8)
                                        : (W_hh2 + r * 128 + (kt - 4) * 32 + q * 8);
            v8s f;
            #pragma unroll
            for (int b = 0; b < 8; ++b) f[b] = (short)f2bf(src[b]);
            w2[tl][kt] = f;
        }
    }
    // x-tile weights for layer 1 (K slots 0..3 of the 32-wide x tile)
    v8s wx[4];
    #pragma unroll
    for (int tl = 0; tl < 4; ++tl) {
        int c = (w * 4 + tl) * 16 + u;
        int r = (c & 3) * 128 + (c >> 2);
        v8s f;
        #pragma unroll
        for (int b = 0; b < 8; ++b) {
            int k = q * 8 + b;
            f[b] = (k < 4) ? (short)f2bf(W_ih1[r * 4 + k]) : (short)0;
        }
        wx[tl] = f;
    }

    // biases (per lane: hidden unit j = w*16 + u), c-state (2 cells/lane/layer)
    const int j = w * 16 + u;
    float b1g_[4], b2g_[4];
    #pragma unroll
    for (int g = 0; g < 4; ++g) {
        b1g_[g] = b_ih1[g * 128 + j] + b_hh1[g * 128 + j];
        b2g_[g] = b_ih2[g * 128 + j] + b_hh2[g * 128 + j];
    }
    float blin = (u < 4) ? b_lin[u] : 0.0f;
    float c1[2], c2[2];
    #pragma unroll
    for (int p = 0; p < 2; ++p) {
        int m = 2 * q + p;
        c1[p] = c0 [(b0 + m) * HIDN + j];
        c2[p] = c02[(b0 + m) * HIDN + j];
    }
    __syncthreads();

    // ---------------- time loop ----------------
    v4f acc2[4];
    float4 xpref;
    for (int t = 0; t < T_STEPS; ++t) {
        // ---- phase A: uses OLD h1/h2 ----
        v8s a2[4];
        #pragma unroll
        for (int kt = 0; kt < 4; ++kt)
            a2[kt] = *(const v8s*)(smem + LDS_H2 + u * HROW + kt * 64 + q * 16);

        // out[t-1] = h2_old @ W_lin^T  (wave 7, extra N-tile)
        if (w == 7) {
            v4f oacc = {0.f, 0.f, 0.f, 0.f};
            #pragma unroll
            for (int kt = 0; kt < 4; ++kt) {
                v8s wlf = *(const v8s*)(smem + LDS_WLIN + (kt << 10) + l * 16);
                oacc = __builtin_amdgcn_mfma_f32_16x16x32_bf16(a2[kt], wlf, oacc, 0, 0, 0);
            }
            if (t > 0 && q < 2 && u < 4) {
                #pragma unroll
                for (int d = 0; d < 4; ++d) {
                    int m = q * 4 + d;
                    out[((long)(t - 1) * BATCH + b0 + m) * 4 + u] = oacc[d] + blin;
                }
            }
        }
        // prefetch x[t+1]
        if (w == 6 && l < 8 && t + 1 < T_STEPS)
            xpref = *(const float4*)(input + ((long)(t + 1) * BATCH + b0 + l) * 4);

        // layer-2, h2 half of K (kt 4..7) into persistent acc2
        #pragma unroll
        for (int tl = 0; tl < 4; ++tl) {
            v4f a = {0.f, 0.f, 0.f, 0.f};
            #pragma unroll
            for (int kt = 0; kt < 4; ++kt)
                a = __builtin_amdgcn_mfma_f32_16x16x32_bf16(a2[kt], w2[tl][kt + 4], a, 0, 0, 0);
            acc2[tl] = a;
        }

        // layer-1 gates: A = [h1_old | x_t(pad 32)]
        v8s a1[5];
        #pragma unroll
        for (int kt = 0; kt < 5; ++kt)
            a1[kt] = *(const v8s*)(smem + LDS_H1 + u * HROW + kt * 64 + q * 16);
        #pragma unroll
        for (int tl = 0; tl < 4; ++tl) {
            v4f a = {0.f, 0.f, 0.f, 0.f};
            #pragma unroll
            for (int kt = 0; kt < 4; ++kt) {
                v8s wf = *(const v8s*)(smem + LDS_W1 + (((w * 4 + tl) * 4 + kt) << 10) + l * 16);
                a = __builtin_amdgcn_mfma_f32_16x16x32_bf16(a1[kt], wf, a, 0, 0, 0);
            }
            a = __builtin_amdgcn_mfma_f32_16x16x32_bf16(a1[4], wx[tl], a, 0, 0, 0);
            if (q < 2) {
                #pragma unroll
                for (int d = 0; d < 4; ++d)
                    gw[(q * 4 + d) * 64 + tl * 16 + u] = a[d];
            }
        }

        __syncthreads();   // barrier 1: all phase-A LDS reads done

        // layer-1 activations (wave-local gate transpose through LDS)
        #pragma unroll
        for (int p = 0; p < 2; ++p) {
            int m = 2 * q + p;
            v4f gv = *(const v4f*)(gw + m * 64 + 4 * u);
            float gi = sigf  (gv[0] + b1g_[0]);
            float gf = sigf  (gv[1] + b1g_[1]);
            float gg = tanhf_(gv[2] + b1g_[2]);
            float go = sigf  (gv[3] + b1g_[3]);
            c1[p] = gf * c1[p] + gi * gg;
            float h = go * tanhf_(c1[p]);
            h1s[m * HROWS + j] = (short)f2bf(h);
        }
        // write x[t+1] into h1 buf x-cols
        if (w == 6 && l < 8 && t + 1 < T_STEPS) {
            ushort4 xb = make_ushort4(f2bf(xpref.x), f2bf(xpref.y), f2bf(xpref.z), f2bf(xpref.w));
            *(ushort4*)(h1s + l * HROWS + 128) = xb;
        }

        __syncthreads();   // barrier 2: h1_new (+x) visible

        // ---- phase B: layer-2, h1 half of K (kt 0..3) ----
        #pragma unroll
        for (int kt = 0; kt < 4; ++kt)
            a2[kt] = *(const v8s*)(smem + LDS_H1 + u * HROW + kt * 64 + q * 16);
        #pragma unroll
        for (int tl = 0; tl < 4; ++tl) {
            v4f a = acc2[tl];
            #pragma unroll
            for (int kt = 0; kt < 4; ++kt)
                a = __builtin_amdgcn_mfma_f32_16x16x32_bf16(a2[kt], w2[tl][kt], a, 0, 0, 0);
            if (q < 2) {
                #pragma unroll
                for (int d = 0; d < 4; ++d)
                    gw[(q * 4 + d) * 64 + tl * 16 + u] = a[d];
            }
        }
        // layer-2 activations
        #pragma unroll
        for (int p = 0; p < 2; ++p) {
            int m = 2 * q + p;
            v4f gv = *(const v4f*)(gw + m * 64 + 4 * u);
            float gi = sigf  (gv[0] + b2g_[0]);
            float gf = sigf  (gv[1] + b2g_[1]);
            float gg = tanhf_(gv[2] + b2g_[2]);
            float go = sigf  (gv[3] + b2g_[3]);
            c2[p] = gf * c2[p] + gi * gg;
            float h = go * tanhf_(c2[p]);
            h2s[m * HROWS + j] = (short)f2bf(h);
        }

        __syncthreads();   // barrier 3: h2_new visible for next step
    }

    // epilogue: out[T-1] from final h2
    if (w == 7) {
        v4f oacc = {0.f, 0.f, 0.f, 0.f};
        #pragma unroll
        for (int kt = 0; kt < 4; ++kt) {
            v8s a   = *(const v8s*)(smem + LDS_H2 + u * HROW + kt * 64 + q * 16);
            v8s wlf = *(const v8s*)(smem + LDS_WLIN + (kt << 10) + l * 16);
            oacc = __builtin_amdgcn_mfma_f32_16x16x32_bf16(a, wlf, oacc, 0, 0, 0);
        }
        if (q < 2 && u < 4) {
            #pragma unroll
            for (int d = 0; d < 4; ++d)
                out[((long)(T_STEPS - 1) * BATCH + b0 + q * 4 + d) * 4 + u] = oacc[d] + blin;
        }
    }
}

extern "C" void kernel_launch(void* const* d_in, const int* in_sizes, int n_in,
                              void* d_out, int out_size, void* d_ws, size_t ws_size,
                              hipStream_t stream) {
    const float* input = (const float*)d_in[0];
    // d_in[1] = future (unused, ==0)
    const float* W_ih1 = (const float*)d_in[2];
    const float* W_hh1 = (const float*)d_in[3];
    const float* b_ih1 = (const float*)d_in[4];
    const float* b_hh1 = (const float*)d_in[5];
    const float* W_ih2 = (const float*)d_in[6];
    const float* W_hh2 = (const float*)d_in[7];
    const float* b_ih2 = (const float*)d_in[8];
    const float* b_hh2 = (const float*)d_in[9];
    const float* W_lin = (const float*)d_in[10];
    const float* b_lin = (const float*)d_in[11];
    const float* h0    = (const float*)d_in[12];
    const float* c0    = (const float*)d_in[13];
    const float* h02   = (const float*)d_in[14];
    const float* c02   = (const float*)d_in[15];
    float* out = (float*)d_out;

    (void)hipFuncSetAttribute((const void*)lstm_seq_kernel,
                              hipFuncAttributeMaxDynamicSharedMemorySize, LDS_TOTAL);
    lstm_seq_kernel<<<BATCH / 8, 512, LDS_TOTAL, stream>>>(
        input, W_ih1, W_hh1, b_ih1, b_hh1, W_ih2, W_hh2, b_ih2, b_hh2,
        W_lin, b_lin, h0, c0, h02, c02, out);
}

// Round 2
// 3563.268 us; speedup vs baseline: 1.6651x; 1.6651x over previous
//
#include <hip/hip_runtime.h>

#define T_STEPS 2048
#define BATCH   2048
#define HIDN    128

typedef short v8s __attribute__((ext_vector_type(8)));
typedef float v4f __attribute__((ext_vector_type(4)));
typedef unsigned short u16;
typedef unsigned int   u32;

// ---------------- LDS layout (bytes) ----------------
// W1 image: 32 tiles x 4 kt x 1KB b-frag chunks   [0, 131072)
// h1 dbuf:  2 x 4KB fragment-order images         [131072, 139264)
// h2 dbuf:  2 x 4KB fragment-order images         [139264, 147456)
#define LDS_W1    0
#define LDS_H1    131072
#define LDS_H2    (131072 + 8192)
#define LDS_TOTAL (131072 + 16384)

__device__ __forceinline__ u16 f2bf(float x) {
    u32 u = __float_as_uint(x);
    u32 r = (u + 0x7FFFu + ((u >> 16) & 1u)) >> 16;
    return (u16)r;
}
__device__ __forceinline__ float rcpf(float x) { return __builtin_amdgcn_rcpf(x); }
__device__ __forceinline__ float sigf(float x) { return rcpf(1.0f + __expf(-x)); }
__device__ __forceinline__ float tanhf_(float x) {
    float e = __expf(2.0f * x);
    return 1.0f - 2.0f * rcpf(e + 1.0f);
}
// byte offset of element (row r, k) inside a 4KB fragment-order image
// (A-frag: lane (u,q) reads 16B at kt*1024 + (q*16+u)*16; element (r,k):
//  lane = ((k>>3)&3)*16 + r, byte = (k&7)*2, chunk = k>>5)
__device__ __forceinline__ int fragoff(int r, int k) {
    return ((k >> 5) << 10) + ((((k >> 3) & 3) * 16 + r) << 4) + ((k & 7) << 1);
}

__global__ __launch_bounds__(512, 2) void lstm_seq_kernel(
    const float* __restrict__ input,
    const float* __restrict__ W_ih1, const float* __restrict__ W_hh1,
    const float* __restrict__ b_ih1, const float* __restrict__ b_hh1,
    const float* __restrict__ W_ih2, const float* __restrict__ W_hh2,
    const float* __restrict__ b_ih2, const float* __restrict__ b_hh2,
    const float* __restrict__ W_lin, const float* __restrict__ b_lin,
    const float* __restrict__ h0,  const float* __restrict__ c0,
    const float* __restrict__ h02, const float* __restrict__ c02,
    float* __restrict__ out)
{
    extern __shared__ char smem[];
    const int tid = threadIdx.x;
    const int w   = tid >> 6;     // wave 0..7
    const int l   = tid & 63;
    const int u   = l & 15;       // MFMA row/col index
    const int q   = l >> 4;       // MFMA quad
    const int b0  = blockIdx.x * 8;
    const bool low = (q < 2);     // q<2: layer-2 cells; q>=2: layer-1 cells
    const int j   = w * 16 + u;   // hidden unit owned by this lane

    // ---------------- init: zero h bufs (16KB) ----------------
    for (int e = tid; e < 4096; e += 512)
        ((float*)(smem + LDS_H1))[e] = 0.0f;
    __syncthreads();
    // preload h0 -> h1buf[1] (rows m and m+8), h02 -> h2buf[1] (rows m)
    for (int e = tid; e < 1024; e += 512) {
        int m = e >> 7, jj = e & 127;
        u16 hv1 = f2bf(h0 [(b0 + m) * HIDN + jj]);
        u16 hv2 = f2bf(h02[(b0 + m) * HIDN + jj]);
        int fo = fragoff(m, jj);
        *(u16*)(smem + LDS_H1 + 4096 + fo)       = hv1;
        *(u16*)(smem + LDS_H1 + 4096 + fo + 128) = hv1;   // row m+8 dup
        *(u16*)(smem + LDS_H2 + 4096 + fo)       = hv2;
    }

    // ---------------- W1 b-frag image in LDS ----------------
    // col permutation: c_local = gate*16 + u  ->  original row r = gate*128 + j
    #pragma unroll
    for (int tl = 0; tl < 4; ++tl) {
        int r = tl * 128 + j;
        #pragma unroll
        for (int kt = 0; kt < 4; ++kt) {
            const float* src = W_hh1 + r * HIDN + kt * 32 + q * 8;
            v8s f;
            #pragma unroll
            for (int b = 0; b < 8; ++b) f[b] = (short)f2bf(src[b]);
            *(v8s*)(smem + LDS_W1 + (((w * 4 + tl) * 4 + kt) << 10) + l * 16) = f;
        }
    }

    // ---------------- resident register fragments ----------------
    // layer-2 weights: kt 0..3 = W_ih2 (A=h1_new), kt 4..7 = W_hh2 (A=h2_old)
    v8s w2[4][8];
    #pragma unroll
    for (int tl = 0; tl < 4; ++tl) {
        int r = tl * 128 + j;
        #pragma unroll
        for (int kt = 0; kt < 8; ++kt) {
            const float* src = (kt < 4) ? (W_ih2 + r * HIDN + kt * 32 + q * 8)
                                        : (W_hh2 + r * HIDN + (kt - 4) * 32 + q * 8);
            v8s f;
            #pragma unroll
            for (int b = 0; b < 8; ++b) f[b] = (short)f2bf(src[b]);
            w2[tl][kt] = f;
        }
    }
    // x-tile weights (K slots 0..3 of a 32-wide tile)
    v8s wx[4];
    #pragma unroll
    for (int tl = 0; tl < 4; ++tl) {
        int r = tl * 128 + j;
        v8s f;
        #pragma unroll
        for (int b = 0; b < 8; ++b) {
            int k = q * 8 + b;
            f[b] = (k < 4) ? (short)f2bf(W_ih1[r * 4 + k]) : (short)0;
        }
        wx[tl] = f;
    }
    // W_lin b-frags (wave 7 only; cols u<4 valid)
    v8s wlin[4];
    if (w == 7) {
        #pragma unroll
        for (int kt = 0; kt < 4; ++kt) {
            v8s f;
            #pragma unroll
            for (int b = 0; b < 8; ++b) {
                int kk = kt * 32 + q * 8 + b;
                f[b] = (u < 4) ? (short)f2bf(W_lin[u * HIDN + kk]) : (short)0;
            }
            wlin[kt] = f;
        }
    }

    // biases + c-state, selected per lane half
    float bg[4];
    #pragma unroll
    for (int g = 0; g < 4; ++g)
        bg[g] = low ? (b_ih2[g * 128 + j] + b_hh2[g * 128 + j])
                    : (b_ih1[g * 128 + j] + b_hh1[g * 128 + j]);
    float blin = (w == 7 && u < 4) ? b_lin[u] : 0.0f;
    float c[4];
    #pragma unroll
    for (int d = 0; d < 4; ++d) {
        int m = low ? (4 * q + d) : (4 * (q - 2) + d);
        c[d] = low ? c02[(b0 + m) * HIDN + j] : c0[(b0 + m) * HIDN + j];
    }
    // x[0] preload (lanes q==0, u>=8 hold batch row u-8)
    float4 xcur = {0, 0, 0, 0}, xnext = {0, 0, 0, 0};
    if (q == 0 && u >= 8)
        xcur = *(const float4*)(input + (long)(b0 + u - 8) * 4);

    const int cb = fragoff(0, j);   // lane-const column part of h-write address
    __syncthreads();

    // ---------------- pipelined time loop: slot s does l1(s) and l2(s-1) ----
    for (int s = 0; s <= T_STEPS; ++s) {
        const char* h1r = smem + LDS_H1 + ((s - 1) & 1) * 4096;  // h1[s-1]
        const char* h2r = smem + LDS_H2 + (s & 1) * 4096;        // h2[s-2]

        v8s a1[4];
        #pragma unroll
        for (int kt = 0; kt < 4; ++kt)
            a1[kt] = *(const v8s*)(h1r + (kt << 10) + l * 16);

        v4f accL2[4], accL1[4];

        // ---- layer 2 for step s-1: A = [h1[s-1] | h2[s-2]] ----
        if (s >= 1) {
            v8s a2[4];
            #pragma unroll
            for (int kt = 0; kt < 4; ++kt)
                a2[kt] = *(const v8s*)(h2r + (kt << 10) + l * 16);
            #pragma unroll
            for (int tl = 0; tl < 4; ++tl) {
                v4f a = {0.f, 0.f, 0.f, 0.f};
                #pragma unroll
                for (int kt = 0; kt < 4; ++kt)
                    a = __builtin_amdgcn_mfma_f32_16x16x32_bf16(a1[kt], w2[tl][kt], a, 0, 0, 0);
                #pragma unroll
                for (int kt = 0; kt < 4; ++kt)
                    a = __builtin_amdgcn_mfma_f32_16x16x32_bf16(a2[kt], w2[tl][kt + 4], a, 0, 0, 0);
                accL2[tl] = a;
            }
            // out[s-2] = h2[s-2] @ W_lin^T (wave 7 extra tile, same A frags)
            if (w == 7 && s >= 2) {
                v4f oa = {0.f, 0.f, 0.f, 0.f};
                #pragma unroll
                for (int kt = 0; kt < 4; ++kt)
                    oa = __builtin_amdgcn_mfma_f32_16x16x32_bf16(a2[kt], wlin[kt], oa, 0, 0, 0);
                if (low && u < 4) {
                    #pragma unroll
                    for (int d = 0; d < 4; ++d)
                        out[((long)(s - 2) * BATCH + b0 + 4 * q + d) * 4 + u] = oa[d] + blin;
                }
            }
        }

        // ---- layer 1 for step s: A = [h1[s-1] | x[s]] (batch in rows 8..15) ----
        if (s < T_STEPS) {
            v8s ax = {0, 0, 0, 0, 0, 0, 0, 0};
            if (q == 0 && u >= 8) {
                ax[0] = (short)f2bf(xcur.x); ax[1] = (short)f2bf(xcur.y);
                ax[2] = (short)f2bf(xcur.z); ax[3] = (short)f2bf(xcur.w);
            }
            if (q == 0 && u >= 8 && s + 1 < T_STEPS)
                xnext = *(const float4*)(input + ((long)(s + 1) * BATCH + b0 + u - 8) * 4);
            #pragma unroll
            for (int tl = 0; tl < 4; ++tl) {
                v4f a = {0.f, 0.f, 0.f, 0.f};
                #pragma unroll
                for (int kt = 0; kt < 4; ++kt) {
                    v8s wf = *(const v8s*)(smem + LDS_W1 + (((w * 4 + tl) * 4 + kt) << 10) + l * 16);
                    a = __builtin_amdgcn_mfma_f32_16x16x32_bf16(a1[kt], wf, a, 0, 0, 0);
                }
                a = __builtin_amdgcn_mfma_f32_16x16x32_bf16(ax, wx[tl], a, 0, 0, 0);
                accL1[tl] = a;
            }
        }

        // ---- combined activation: q<2 -> layer2 cells, q>=2 -> layer1 cells ----
        bool act_en = low ? (s >= 1) : (s < T_STEPS);
        if (act_en) {
            int rbase = low ? (4 * q) : (4 * (q - 2));
            char* hw = (char*)smem + (low ? (LDS_H2 + ((s - 1) & 1) * 4096)
                                          : (LDS_H1 + (s & 1) * 4096));
            #pragma unroll
            for (int d = 0; d < 4; ++d) {
                float gI = (low ? accL2[0][d] : accL1[0][d]) + bg[0];
                float gF = (low ? accL2[1][d] : accL1[1][d]) + bg[1];
                float gG = (low ? accL2[2][d] : accL1[2][d]) + bg[2];
                float gO = (low ? accL2[3][d] : accL1[3][d]) + bg[3];
                float si = sigf(gI), sf = sigf(gF), tg = tanhf_(gG), so = sigf(gO);
                c[d] = sf * c[d] + si * tg;
                float h = so * tanhf_(c[d]);
                u16 hb = f2bf(h);
                int r = rbase + d;
                *(u16*)(hw + cb + (r << 4)) = hb;
                if (!low) *(u16*)(hw + cb + (r << 4) + 128) = hb;  // dup row m+8
            }
        }
        xcur = xnext;
        __syncthreads();
    }

    // epilogue: out[T-1] from h2[T-1] (written in slot T, visible after barrier)
    if (w == 7) {
        const char* h2r = smem + LDS_H2 + ((T_STEPS - 1) & 1) * 4096;
        v4f oa = {0.f, 0.f, 0.f, 0.f};
        #pragma unroll
        for (int kt = 0; kt < 4; ++kt) {
            v8s a = *(const v8s*)(h2r + (kt << 10) + l * 16);
            oa = __builtin_amdgcn_mfma_f32_16x16x32_bf16(a, wlin[kt], oa, 0, 0, 0);
        }
        if (low && u < 4) {
            #pragma unroll
            for (int d = 0; d < 4; ++d)
                out[((long)(T_STEPS - 1) * BATCH + b0 + 4 * q + d) * 4 + u] = oa[d] + blin;
        }
    }
}

extern "C" void kernel_launch(void* const* d_in, const int* in_sizes, int n_in,
                              void* d_out, int out_size, void* d_ws, size_t ws_size,
                              hipStream_t stream) {
    const float* input = (const float*)d_in[0];
    // d_in[1] = future (unused, ==0)
    const float* W_ih1 = (const float*)d_in[2];
    const float* W_hh1 = (const float*)d_in[3];
    const float* b_ih1 = (const float*)d_in[4];
    const float* b_hh1 = (const float*)d_in[5];
    const float* W_ih2 = (const float*)d_in[6];
    const float* W_hh2 = (const float*)d_in[7];
    const float* b_ih2 = (const float*)d_in[8];
    const float* b_hh2 = (const float*)d_in[9];
    const float* W_lin = (const float*)d_in[10];
    const float* b_lin = (const float*)d_in[11];
    const float* h0    = (const float*)d_in[12];
    const float* c0    = (const float*)d_in[13];
    const float* h02   = (const float*)d_in[14];
    const float* c02   = (const float*)d_in[15];
    float* out = (float*)d_out;

    (void)hipFuncSetAttribute((const void*)lstm_seq_kernel,
                              hipFuncAttributeMaxDynamicSharedMemorySize, LDS_TOTAL);
    lstm_seq_kernel<<<BATCH / 8, 512, LDS_TOTAL, stream>>>(
        input, W_ih1, W_hh1, b_ih1, b_hh1, W_ih2, W_hh2, b_ih2, b_hh2,
        W_lin, b_lin, h0, c0, h02, c02, out);
}